// Round 2
// baseline (156.476 us; speedup 1.0000x reference)
//
#include <hip/hip_runtime.h>

#define N_POINTS   100000
#define N_EVENTS   1000000
#define N_PAIRS    100000
#define N_RIEMANN  128
#define EPS_F      1e-6f
#define NON_EVENT_W 1.0f

constexpr int BLOCK = 256;
constexpr int PREP_BLOCKS = (N_POINTS + BLOCK - 1) / BLOCK;   // 391
constexpr int EV_BLOCKS   = (N_EVENTS + BLOCK - 1) / BLOCK;   // 3907, 1 thread/event
constexpr int PAIR_BLOCKS = (N_PAIRS + BLOCK - 1) / BLOCK;    // 391, 1 thread/pair
constexpr int MAIN_BLOCKS = EV_BLOCKS + PAIR_BLOCKS;

// 32B interleaved point record: one 64B cache line covers 2 points.
// pt4[2*i]   = (z.x, z.y, v.x, v.y)
// pt4[2*i+1] = (a.x, a.y, 0, 0)

__device__ __forceinline__ float block_reduce_sum(float v) {
    #pragma unroll
    for (int off = 32; off > 0; off >>= 1)
        v += __shfl_down(v, off, 64);
    __shared__ float smem[BLOCK / 64];
    const int lane = threadIdx.x & 63;
    const int wid  = threadIdx.x >> 6;
    if (lane == 0) smem[wid] = v;
    __syncthreads();
    float r = 0.f;
    if (threadIdx.x == 0) {
        #pragma unroll
        for (int i = 0; i < BLOCK / 64; ++i) r += smem[i];
    }
    return r;
}

__global__ __launch_bounds__(BLOCK) void prep_kernel(
    const float2* __restrict__ z0,
    const float2* __restrict__ v0,
    const float2* __restrict__ a0,
    const float*  __restrict__ beta,
    float4*       __restrict__ pts,   // 2*N_POINTS float4
    float*        __restrict__ out)
{
    const int i = blockIdx.x * BLOCK + threadIdx.x;
    if (i < N_POINTS) {
        const float2 z = z0[i], v = v0[i], a = a0[i];
        pts[2 * i]     = make_float4(z.x, z.y, v.x, v.y);
        pts[2 * i + 1] = make_float4(a.x, a.y, 0.f, 0.f);
    }
    if (blockIdx.x == 0 && threadIdx.x == 0)
        out[0] = beta[0] * (float)N_EVENTS;   // atomics accumulate on top
}

template <bool INTERLEAVED>
__global__ __launch_bounds__(BLOCK) void main_kernel(
    const float4* __restrict__ pts,    // interleaved (valid iff INTERLEAVED)
    const float2* __restrict__ z0,
    const float2* __restrict__ v0,
    const float2* __restrict__ a0,
    const float*  __restrict__ beta,
    const int*    __restrict__ eu,
    const int*    __restrict__ ev,
    const float*  __restrict__ et,
    const int*    __restrict__ pu,
    const int*    __restrict__ pv,
    const float*  __restrict__ t0p,
    const float*  __restrict__ tnp,
    float*        __restrict__ out)
{
    float acc = 0.f;
    const int b = blockIdx.x;

    if (b < EV_BLOCKS) {
        // ---- event term: one thread per event ----
        const int i = b * BLOCK + threadIdx.x;
        if (i < N_EVENTS) {
            const int iu = eu[i];
            const int iv = ev[i];
            const float te = et[i];
            float dzx, dzy, dvx, dvy, dax, day;
            if (INTERLEAVED) {
                const float4 u0 = pts[2 * iu];     // z,v of u  (same 64B line)
                const float4 u1 = pts[2 * iu + 1]; // a of u
                const float4 w0 = pts[2 * iv];
                const float4 w1 = pts[2 * iv + 1];
                dzx = u0.x - w0.x; dzy = u0.y - w0.y;
                dvx = u0.z - w0.z; dvy = u0.w - w0.w;
                dax = u1.x - w1.x; day = u1.y - w1.y;
            } else {
                const float2 zu = z0[iu], zv = z0[iv];
                const float2 vu = v0[iu], vv = v0[iv];
                const float2 au = a0[iu], av = a0[iv];
                dzx = zu.x - zv.x; dzy = zu.y - zv.y;
                dvx = vu.x - vv.x; dvy = vu.y - vv.y;
                dax = au.x - av.x; day = au.y - av.y;
            }
            const float h = 0.5f * te * te;
            const float dx = dzx + dvx * te + dax * h + EPS_F;
            const float dy = dzy + dvy * te + day * h + EPS_F;
            acc = -sqrtf(dx * dx + dy * dy);
        }
    } else {
        // ---- non-event term: one thread per pair, 128-step Riemann sum ----
        const int p = (b - EV_BLOCKS) * BLOCK + threadIdx.x;
        if (p < N_PAIRS) {
            const float t0v = t0p[0];
            const float tnv = tnp[0];
            const float dt  = (tnv - t0v) * (1.0f / N_RIEMANN);
            const float bb  = beta[0];
            const int iu = pu[p];
            const int iv = pv[p];
            float dzx, dzy, dvx, dvy, dax, day;
            if (INTERLEAVED) {
                const float4 u0 = pts[2 * iu];
                const float4 u1 = pts[2 * iu + 1];
                const float4 w0 = pts[2 * iv];
                const float4 w1 = pts[2 * iv + 1];
                dzx = u0.x - w0.x; dzy = u0.y - w0.y;
                dvx = u0.z - w0.z; dvy = u0.w - w0.w;
                dax = u1.x - w1.x; day = u1.y - w1.y;
            } else {
                const float2 zu = z0[iu], zv = z0[iv];
                const float2 vu = v0[iu], vv = v0[iv];
                const float2 au = a0[iu], av = a0[iv];
                dzx = zu.x - zv.x; dzy = zu.y - zv.y;
                dvx = vu.x - vv.x; dvy = vu.y - vv.y;
                dax = au.x - av.x; day = au.y - av.y;
            }
            const float eb = __expf(bb);
            float s = 0.f;
            #pragma unroll 4
            for (int k = 0; k < N_RIEMANN; ++k) {
                const float t = t0v + (float)k * (1.0f / N_RIEMANN) * (tnv - t0v);
                const float h = 0.5f * t * t;
                const float dx = dzx + dvx * t + dax * h + EPS_F;
                const float dy = dzy + dvy * t + day * h + EPS_F;
                s += __expf(-sqrtf(dx * dx + dy * dy));
            }
            acc = -NON_EVENT_W * dt * eb * s;
        }
    }

    const float r = block_reduce_sum(acc);
    if (threadIdx.x == 0) atomicAdd(out, r);
}

extern "C" void kernel_launch(void* const* d_in, const int* in_sizes, int n_in,
                              void* d_out, int out_size, void* d_ws, size_t ws_size,
                              hipStream_t stream) {
    const float*  beta = (const float*)d_in[0];
    const float2* z0   = (const float2*)d_in[1];
    const float2* v0   = (const float2*)d_in[2];
    const float2* a0   = (const float2*)d_in[3];
    const int*    eu   = (const int*)d_in[4];
    const int*    ev   = (const int*)d_in[5];
    const float*  et   = (const float*)d_in[6];
    const int*    pu   = (const int*)d_in[7];
    const int*    pv   = (const int*)d_in[8];
    const float*  t0p  = (const float*)d_in[9];
    const float*  tnp  = (const float*)d_in[10];

    float*  out = (float*)d_out;
    float4* pts = (float4*)d_ws;
    const bool interleave = (ws_size >= (size_t)(2 * N_POINTS) * sizeof(float4));

    // prep writes out[0] = beta*N_EVENTS and (if room) the interleaved points
    if (interleave) {
        prep_kernel<<<PREP_BLOCKS, BLOCK, 0, stream>>>(z0, v0, a0, beta, pts, out);
        main_kernel<true><<<MAIN_BLOCKS, BLOCK, 0, stream>>>(
            pts, z0, v0, a0, beta, eu, ev, et, pu, pv, t0p, tnp, out);
    } else {
        prep_kernel<<<1, BLOCK, 0, stream>>>(z0, v0, a0, beta, pts, out); // only out-init matters
        main_kernel<false><<<MAIN_BLOCKS, BLOCK, 0, stream>>>(
            pts, z0, v0, a0, beta, eu, ev, et, pu, pv, t0p, tnp, out);
    }
}

// Round 3
// 109.552 us; speedup vs baseline: 1.4283x; 1.4283x over previous
//
#include <hip/hip_runtime.h>
#include <hip/hip_fp16.h>

#define N_POINTS   100000
#define N_EVENTS   1000000
#define N_PAIRS    100000
#define N_RIEMANN  128
#define EPS_F      1e-6f
#define NON_EVENT_W 1.0f

constexpr int BLOCK       = 256;
constexpr int EVPT        = 4;                                  // events per thread
constexpr int EV_THREADS  = N_EVENTS / EVPT;                    // 250000 (exact)
constexpr int EV_BLOCKS   = (EV_THREADS + BLOCK - 1) / BLOCK;   // 977
constexpr int PAIR_BLOCKS = (N_PAIRS + BLOCK - 1) / BLOCK;      // 391
constexpr int MAIN_BLOCKS = PAIR_BLOCKS + EV_BLOCKS;            // pairs FIRST (long latency)
constexpr int PREP_BLOCKS = (N_POINTS + BLOCK - 1) / BLOCK;

// Packed point record (16 B): half2 z | half2 v | half2 a | pad.
// One dwordx4 gather fetches a whole point; 4 points per 64 B line.

__device__ __forceinline__ float block_reduce_sum(float v) {
    #pragma unroll
    for (int off = 32; off > 0; off >>= 1)
        v += __shfl_down(v, off, 64);
    __shared__ float smem[BLOCK / 64];
    const int lane = threadIdx.x & 63;
    const int wid  = threadIdx.x >> 6;
    if (lane == 0) smem[wid] = v;
    __syncthreads();
    float r = 0.f;
    if (threadIdx.x == 0) {
        #pragma unroll
        for (int i = 0; i < BLOCK / 64; ++i) r += smem[i];
    }
    return r;
}

__device__ __forceinline__ void decode_rec(const float4& r, float2& z, float2& v, float2& a) {
    z = __half22float2(*reinterpret_cast<const __half2*>(&r.x));
    v = __half22float2(*reinterpret_cast<const __half2*>(&r.y));
    a = __half22float2(*reinterpret_cast<const __half2*>(&r.z));
}

__global__ __launch_bounds__(BLOCK) void prep_kernel(
    const float2* __restrict__ z0,
    const float2* __restrict__ v0,
    const float2* __restrict__ a0,
    const float*  __restrict__ beta,
    float4*       __restrict__ pts,
    float*        __restrict__ out)
{
    const int i = blockIdx.x * BLOCK + threadIdx.x;
    if (i < N_POINTS) {
        const float2 z = z0[i], v = v0[i], a = a0[i];
        float4 r;
        *reinterpret_cast<__half2*>(&r.x) = __float22half2_rn(make_float2(z.x, z.y));
        *reinterpret_cast<__half2*>(&r.y) = __float22half2_rn(make_float2(v.x, v.y));
        *reinterpret_cast<__half2*>(&r.z) = __float22half2_rn(make_float2(a.x, a.y));
        r.w = 0.f;
        pts[i] = r;
    }
    if (blockIdx.x == 0 && threadIdx.x == 0)
        out[0] = beta[0] * (float)N_EVENTS;   // block atomics accumulate on top
}

template <bool PACKED>
__global__ __launch_bounds__(BLOCK) void main_kernel(
    const float4* __restrict__ pts,
    const float2* __restrict__ z0,
    const float2* __restrict__ v0,
    const float2* __restrict__ a0,
    const float*  __restrict__ beta,
    const int*    __restrict__ eu,
    const int*    __restrict__ ev,
    const float*  __restrict__ et,
    const int*    __restrict__ pu,
    const int*    __restrict__ pv,
    const float*  __restrict__ t0p,
    const float*  __restrict__ tnp,
    float*        __restrict__ out)
{
    float acc = 0.f;
    const int b = blockIdx.x;

    if (b < PAIR_BLOCKS) {
        // ---- non-event term (long 128-step loop): scheduled FIRST ----
        const int p = b * BLOCK + threadIdx.x;
        if (p < N_PAIRS) {
            const float t0v = t0p[0];
            const float tnv = tnp[0];
            const float dt  = (tnv - t0v) * (1.0f / N_RIEMANN);
            const float bb  = beta[0];
            const int iu = pu[p];
            const int iv = pv[p];
            float dzx, dzy, dvx, dvy, dax, day;
            if (PACKED) {
                const float4 ru = pts[iu];
                const float4 rv = pts[iv];
                float2 zu, vu, au, zv, vv, av;
                decode_rec(ru, zu, vu, au);
                decode_rec(rv, zv, vv, av);
                dzx = zu.x - zv.x; dzy = zu.y - zv.y;
                dvx = vu.x - vv.x; dvy = vu.y - vv.y;
                dax = au.x - av.x; day = au.y - av.y;
            } else {
                const float2 zu = z0[iu], zv = z0[iv];
                const float2 vu = v0[iu], vv = v0[iv];
                const float2 au = a0[iu], av = a0[iv];
                dzx = zu.x - zv.x; dzy = zu.y - zv.y;
                dvx = vu.x - vv.x; dvy = vu.y - vv.y;
                dax = au.x - av.x; day = au.y - av.y;
            }
            const float eb = __expf(bb);
            float s = 0.f;
            #pragma unroll 4
            for (int k = 0; k < N_RIEMANN; ++k) {
                const float t = t0v + (float)k * (1.0f / N_RIEMANN) * (tnv - t0v);
                const float h = 0.5f * t * t;
                const float dx = dzx + dvx * t + dax * h + EPS_F;
                const float dy = dzy + dvy * t + day * h + EPS_F;
                s += __expf(-sqrtf(dx * dx + dy * dy));
            }
            acc = -NON_EVENT_W * dt * eb * s;
        }
    } else {
        // ---- event term: EVPT events per thread, batched loads for MLP ----
        const int t = (b - PAIR_BLOCKS) * BLOCK + threadIdx.x;
        if (t < EV_THREADS) {
            int iu[EVPT], iv[EVPT];
            float te[EVPT];
            #pragma unroll
            for (int j = 0; j < EVPT; ++j) {
                const int i = t + j * EV_THREADS;   // all < N_EVENTS, coalesced
                iu[j] = eu[i];
                iv[j] = ev[i];
                te[j] = et[i];
            }
            if (PACKED) {
                float4 ru[EVPT], rv[EVPT];
                #pragma unroll
                for (int j = 0; j < EVPT; ++j) ru[j] = pts[iu[j]];
                #pragma unroll
                for (int j = 0; j < EVPT; ++j) rv[j] = pts[iv[j]];
                #pragma unroll
                for (int j = 0; j < EVPT; ++j) {
                    float2 zu, vu, au, zv, vv, av;
                    decode_rec(ru[j], zu, vu, au);
                    decode_rec(rv[j], zv, vv, av);
                    const float h = 0.5f * te[j] * te[j];
                    const float dx = (zu.x - zv.x) + (vu.x - vv.x) * te[j] + (au.x - av.x) * h + EPS_F;
                    const float dy = (zu.y - zv.y) + (vu.y - vv.y) * te[j] + (au.y - av.y) * h + EPS_F;
                    acc -= sqrtf(dx * dx + dy * dy);
                }
            } else {
                float2 zu[EVPT], zv[EVPT], vu[EVPT], vv[EVPT], au[EVPT], av[EVPT];
                #pragma unroll
                for (int j = 0; j < EVPT; ++j) { zu[j] = z0[iu[j]]; zv[j] = z0[iv[j]]; }
                #pragma unroll
                for (int j = 0; j < EVPT; ++j) { vu[j] = v0[iu[j]]; vv[j] = v0[iv[j]]; }
                #pragma unroll
                for (int j = 0; j < EVPT; ++j) { au[j] = a0[iu[j]]; av[j] = a0[iv[j]]; }
                #pragma unroll
                for (int j = 0; j < EVPT; ++j) {
                    const float h = 0.5f * te[j] * te[j];
                    const float dx = (zu[j].x - zv[j].x) + (vu[j].x - vv[j].x) * te[j] + (au[j].x - av[j].x) * h + EPS_F;
                    const float dy = (zu[j].y - zv[j].y) + (vu[j].y - vv[j].y) * te[j] + (au[j].y - av[j].y) * h + EPS_F;
                    acc -= sqrtf(dx * dx + dy * dy);
                }
            }
        }
    }

    const float r = block_reduce_sum(acc);
    if (threadIdx.x == 0) atomicAdd(out, r);
}

extern "C" void kernel_launch(void* const* d_in, const int* in_sizes, int n_in,
                              void* d_out, int out_size, void* d_ws, size_t ws_size,
                              hipStream_t stream) {
    const float*  beta = (const float*)d_in[0];
    const float2* z0   = (const float2*)d_in[1];
    const float2* v0   = (const float2*)d_in[2];
    const float2* a0   = (const float2*)d_in[3];
    const int*    eu   = (const int*)d_in[4];
    const int*    ev   = (const int*)d_in[5];
    const float*  et   = (const float*)d_in[6];
    const int*    pu   = (const int*)d_in[7];
    const int*    pv   = (const int*)d_in[8];
    const float*  t0p  = (const float*)d_in[9];
    const float*  tnp  = (const float*)d_in[10];

    float*  out = (float*)d_out;
    float4* pts = (float4*)d_ws;
    const bool packed = (ws_size >= (size_t)N_POINTS * sizeof(float4));

    if (packed) {
        prep_kernel<<<PREP_BLOCKS, BLOCK, 0, stream>>>(z0, v0, a0, beta, pts, out);
        main_kernel<true><<<MAIN_BLOCKS, BLOCK, 0, stream>>>(
            pts, z0, v0, a0, beta, eu, ev, et, pu, pv, t0p, tnp, out);
    } else {
        prep_kernel<<<1, BLOCK, 0, stream>>>(z0, v0, a0, beta, pts, out); // out-init only
        main_kernel<false><<<MAIN_BLOCKS, BLOCK, 0, stream>>>(
            pts, z0, v0, a0, beta, eu, ev, et, pu, pv, t0p, tnp, out);
    }
}

// Round 4
// 105.266 us; speedup vs baseline: 1.4865x; 1.0407x over previous
//
#include <hip/hip_runtime.h>
#include <hip/hip_fp16.h>

#define N_POINTS   100000
#define N_EVENTS   1000000
#define N_PAIRS    100000
#define N_RIEMANN  128
#define EPS_F      1e-6f
#define NON_EVENT_W 1.0f

constexpr int BLOCK       = 256;
constexpr int EVPT        = 8;                                  // events per thread (contiguous)
constexpr int EV_THREADS  = N_EVENTS / EVPT;                    // 125000 (exact)
constexpr int EV_BLOCKS   = (EV_THREADS + BLOCK - 1) / BLOCK;   // 489
constexpr int PAIR_BLOCKS = (N_PAIRS + BLOCK - 1) / BLOCK;      // 391
constexpr int MAIN_BLOCKS = PAIR_BLOCKS + EV_BLOCKS;            // 880; pairs FIRST
constexpr int PREP_BLOCKS = (N_POINTS + BLOCK - 1) / BLOCK;

// Packed point record (16 B): half2 z | half2 v | half2 a | pad.
// One dwordx4 gather per point; 4 points per 64 B line; table = 1.6 MB (L2-resident).

__device__ __forceinline__ float block_reduce_sum(float v) {
    #pragma unroll
    for (int off = 32; off > 0; off >>= 1)
        v += __shfl_down(v, off, 64);
    __shared__ float smem[BLOCK / 64];
    const int lane = threadIdx.x & 63;
    const int wid  = threadIdx.x >> 6;
    if (lane == 0) smem[wid] = v;
    __syncthreads();
    float r = 0.f;
    if (threadIdx.x == 0) {
        #pragma unroll
        for (int i = 0; i < BLOCK / 64; ++i) r += smem[i];
    }
    return r;
}

__device__ __forceinline__ void decode_rec(const float4& r, float2& z, float2& v, float2& a) {
    z = __half22float2(*reinterpret_cast<const __half2*>(&r.x));
    v = __half22float2(*reinterpret_cast<const __half2*>(&r.y));
    a = __half22float2(*reinterpret_cast<const __half2*>(&r.z));
}

__global__ __launch_bounds__(BLOCK) void prep_kernel(
    const float2* __restrict__ z0,
    const float2* __restrict__ v0,
    const float2* __restrict__ a0,
    float4*       __restrict__ pts)
{
    const int i = blockIdx.x * BLOCK + threadIdx.x;
    if (i < N_POINTS) {
        const float2 z = z0[i], v = v0[i], a = a0[i];
        float4 r;
        *reinterpret_cast<__half2*>(&r.x) = __float22half2_rn(make_float2(z.x, z.y));
        *reinterpret_cast<__half2*>(&r.y) = __float22half2_rn(make_float2(v.x, v.y));
        *reinterpret_cast<__half2*>(&r.z) = __float22half2_rn(make_float2(a.x, a.y));
        r.w = 0.f;
        pts[i] = r;
    }
}

template <bool PACKED>
__global__ __launch_bounds__(BLOCK) void main_kernel(
    const float4* __restrict__ pts,
    const float2* __restrict__ z0,
    const float2* __restrict__ v0,
    const float2* __restrict__ a0,
    const float*  __restrict__ beta,
    const int*    __restrict__ eu,
    const int*    __restrict__ ev,
    const float*  __restrict__ et,
    const int*    __restrict__ pu,
    const int*    __restrict__ pv,
    const float*  __restrict__ t0p,
    const float*  __restrict__ tnp,
    float*        __restrict__ partials)
{
    float acc = 0.f;
    const int b = blockIdx.x;

    if (b < PAIR_BLOCKS) {
        // ---- non-event term (long 128-step loop): scheduled FIRST ----
        const int p = b * BLOCK + threadIdx.x;
        if (p < N_PAIRS) {
            const float t0v = t0p[0];
            const float tnv = tnp[0];
            const float dt  = (tnv - t0v) * (1.0f / N_RIEMANN);
            const float bb  = beta[0];
            const int iu = pu[p];
            const int iv = pv[p];
            float dzx, dzy, dvx, dvy, dax, day;
            if (PACKED) {
                const float4 ru = pts[iu];
                const float4 rv = pts[iv];
                float2 zu, vu, au, zv, vv, av;
                decode_rec(ru, zu, vu, au);
                decode_rec(rv, zv, vv, av);
                dzx = zu.x - zv.x; dzy = zu.y - zv.y;
                dvx = vu.x - vv.x; dvy = vu.y - vv.y;
                dax = au.x - av.x; day = au.y - av.y;
            } else {
                const float2 zu = z0[iu], zv = z0[iv];
                const float2 vu = v0[iu], vv = v0[iv];
                const float2 au = a0[iu], av = a0[iv];
                dzx = zu.x - zv.x; dzy = zu.y - zv.y;
                dvx = vu.x - vv.x; dvy = vu.y - vv.y;
                dax = au.x - av.x; day = au.y - av.y;
            }
            const float eb = __expf(bb);
            float s = 0.f;
            #pragma unroll 4
            for (int k = 0; k < N_RIEMANN; ++k) {
                const float t = t0v + (float)k * (1.0f / N_RIEMANN) * (tnv - t0v);
                const float h = 0.5f * t * t;
                const float dx = dzx + dvx * t + dax * h + EPS_F;
                const float dy = dzy + dvy * t + day * h + EPS_F;
                s += __expf(-sqrtf(dx * dx + dy * dy));
            }
            acc = -NON_EVENT_W * dt * eb * s;
        }
    } else {
        // ---- event term: 8 contiguous events/thread; vectorized streams + 16 gathers in flight ----
        const int t = (b - PAIR_BLOCKS) * BLOCK + threadIdx.x;
        if (t < EV_THREADS) {
            const int4*   eu4 = reinterpret_cast<const int4*>(eu);
            const int4*   ev4 = reinterpret_cast<const int4*>(ev);
            const float4* et4 = reinterpret_cast<const float4*>(et);
            const int4 u0 = eu4[2 * t], u1 = eu4[2 * t + 1];
            const int4 w0 = ev4[2 * t], w1 = ev4[2 * t + 1];
            const float4 t0q = et4[2 * t], t1q = et4[2 * t + 1];
            const int iu[EVPT] = { u0.x, u0.y, u0.z, u0.w, u1.x, u1.y, u1.z, u1.w };
            const int iv[EVPT] = { w0.x, w0.y, w0.z, w0.w, w1.x, w1.y, w1.z, w1.w };
            const float te[EVPT] = { t0q.x, t0q.y, t0q.z, t0q.w, t1q.x, t1q.y, t1q.z, t1q.w };
            if (PACKED) {
                float4 ru[EVPT], rv[EVPT];
                #pragma unroll
                for (int j = 0; j < EVPT; ++j) ru[j] = pts[iu[j]];
                #pragma unroll
                for (int j = 0; j < EVPT; ++j) rv[j] = pts[iv[j]];
                #pragma unroll
                for (int j = 0; j < EVPT; ++j) {
                    float2 zu, vu, au, zv, vv, av;
                    decode_rec(ru[j], zu, vu, au);
                    decode_rec(rv[j], zv, vv, av);
                    const float h = 0.5f * te[j] * te[j];
                    const float dx = (zu.x - zv.x) + (vu.x - vv.x) * te[j] + (au.x - av.x) * h + EPS_F;
                    const float dy = (zu.y - zv.y) + (vu.y - vv.y) * te[j] + (au.y - av.y) * h + EPS_F;
                    acc -= sqrtf(dx * dx + dy * dy);
                }
            } else {
                #pragma unroll
                for (int j = 0; j < EVPT; ++j) {
                    const float2 zu = z0[iu[j]], zv = z0[iv[j]];
                    const float2 vu = v0[iu[j]], vv = v0[iv[j]];
                    const float2 au = a0[iu[j]], av = a0[iv[j]];
                    const float h = 0.5f * te[j] * te[j];
                    const float dx = (zu.x - zv.x) + (vu.x - vv.x) * te[j] + (au.x - av.x) * h + EPS_F;
                    const float dy = (zu.y - zv.y) + (vu.y - vv.y) * te[j] + (au.y - av.y) * h + EPS_F;
                    acc -= sqrtf(dx * dx + dy * dy);
                }
            }
        }
    }

    const float r = block_reduce_sum(acc);
    if (threadIdx.x == 0) partials[blockIdx.x] = r;   // no atomics — no serialization
}

__global__ __launch_bounds__(BLOCK) void reduce_kernel(
    const float* __restrict__ partials,
    const float* __restrict__ beta,
    float*       __restrict__ out)
{
    float acc = 0.f;
    for (int i = threadIdx.x; i < MAIN_BLOCKS; i += BLOCK) acc += partials[i];
    const float r = block_reduce_sum(acc);
    if (threadIdx.x == 0) out[0] = beta[0] * (float)N_EVENTS + r;
}

extern "C" void kernel_launch(void* const* d_in, const int* in_sizes, int n_in,
                              void* d_out, int out_size, void* d_ws, size_t ws_size,
                              hipStream_t stream) {
    const float*  beta = (const float*)d_in[0];
    const float2* z0   = (const float2*)d_in[1];
    const float2* v0   = (const float2*)d_in[2];
    const float2* a0   = (const float2*)d_in[3];
    const int*    eu   = (const int*)d_in[4];
    const int*    ev   = (const int*)d_in[5];
    const float*  et   = (const float*)d_in[6];
    const int*    pu   = (const int*)d_in[7];
    const int*    pv   = (const int*)d_in[8];
    const float*  t0p  = (const float*)d_in[9];
    const float*  tnp  = (const float*)d_in[10];

    float* out = (float*)d_out;
    const size_t pts_bytes = (size_t)N_POINTS * sizeof(float4);
    const bool packed = (ws_size >= pts_bytes + (size_t)MAIN_BLOCKS * sizeof(float));

    if (packed) {
        float4* pts      = (float4*)d_ws;
        float*  partials = (float*)((char*)d_ws + pts_bytes);
        prep_kernel<<<PREP_BLOCKS, BLOCK, 0, stream>>>(z0, v0, a0, pts);
        main_kernel<true><<<MAIN_BLOCKS, BLOCK, 0, stream>>>(
            pts, z0, v0, a0, beta, eu, ev, et, pu, pv, t0p, tnp, partials);
        reduce_kernel<<<1, BLOCK, 0, stream>>>(partials, beta, out);
    } else {
        float* partials = (float*)d_ws;       // needs only 3.5 KB
        main_kernel<false><<<MAIN_BLOCKS, BLOCK, 0, stream>>>(
            nullptr, z0, v0, a0, beta, eu, ev, et, pu, pv, t0p, tnp, partials);
        reduce_kernel<<<1, BLOCK, 0, stream>>>(partials, beta, out);
    }
}